// Round 4
// baseline (401.930 us; speedup 1.0000x reference)
//
#include <hip/hip_runtime.h>
#include <math.h>

// Problem constants (from reference setup_inputs)
#define Bb 8
#define Cc 24
#define Hh 320
#define Ww 640
#define HWp (Hh * Ww)        // 204800
#define NPIX (Bb * HWp)      // 1638400
#define BLK 256
#define Gg 2                 // float4 groups per thread -> 8 px/thread
#define WAVE_PX 512          // 64 lanes * 4 px * Gg : contiguous stripe per wave
#define TILE (4 * WAVE_PX)   // 2048 px per 4-wave block

// v5: cross-PIXEL MLP instead of cross-CHANNEL MLP.
// v1-v4 (serial float4 / register batch / fenced batch / async LDS queue with
// guaranteed 24 loads in flight) ALL pin at 1.5-1.6 TB/s. v4 proved in-flight
// bytes per CU (~100 KB) don't move the floor -> queueing on a pattern-
// dependent stage. Shared suspect: all 24 per-wave loads hit the SAME L1 set
// group (plane stride 819200 = 25*32768 === 0 mod 32KB L1) and per-plane runs
// are only 1KB before an 800KB hop (DRAM row thrash). This version: each wave
// owns a 512-px stripe; per channel it reads 2 dwordx4 instrs = 2KB contiguous
// (the 2 groups are 1KB apart -> DIFFERENT L1 sets), 1-deep channel pipeline
// pinned with sched_barrier(0). Low reg pressure so the fence isn't fought.

__global__ __launch_bounds__(BLK) void sparse_regression_kernel(
    const float* __restrict__ cost,
    const float* __restrict__ disp,
    float* __restrict__ pred,   // [B,H,W]   = NPIX floats
    float* __restrict__ prob)   // [B,2,H,W] = 2*NPIX floats
{
    const int lane = threadIdx.x & 63;
    const int wid  = threadIdx.x >> 6;
    // Wave's first pixel. HWp % WAVE_PX == 0 -> a wave never straddles b.
    const int p00  = blockIdx.x * TILE + wid * WAVE_PX;
    const int b    = p00 / HWp;
    const int qw   = p00 - b * HWp;
    const size_t pbase = (size_t)b * Cc * HWp;

    const float* cb[Gg];
    const float* db[Gg];
#pragma unroll
    for (int j = 0; j < Gg; ++j) {
        const int qj = qw + j * 256 + lane * 4;   // group j: lanes contiguous (1KB/instr)
        cb[j] = cost + pbase + qj;
        db[j] = disp + pbase + qj;
    }

    float max1[Gg][4], max2[Gg][4];
    int   idx1[Gg][4], idx2[Gg][4];
#pragma unroll
    for (int j = 0; j < Gg; ++j)
#pragma unroll
        for (int k = 0; k < 4; ++k) {
            max1[j][k] = -INFINITY; max2[j][k] = -INFINITY;
            idx1[j][k] = 0;         idx2[j][k] = 0;
        }

    // ---- Channel scan, 1-deep software pipeline.
    // Iteration c: issue channel c+1's 2 loads, fence, consume channel c.
    // sched_barrier(0) forbids the scheduler from sinking the issued loads
    // down to their (next-iteration) uses -> >=2KB always in flight. ----
    float4 a[Gg];
#pragma unroll
    for (int j = 0; j < Gg; ++j) a[j] = *(const float4*)(cb[j]);
    __builtin_amdgcn_sched_barrier(0);

#pragma unroll
    for (int c = 0; c < Cc; ++c) {
        float4 n[Gg];
        if (c + 1 < Cc) {
#pragma unroll
            for (int j = 0; j < Gg; ++j)
                n[j] = *(const float4*)(cb[j] + (size_t)(c + 1) * HWp);
        }
        __builtin_amdgcn_sched_barrier(0);

        // Consume channel c. Strict '>' scanning c ascending reproduces
        // lax.top_k's lower-index-wins tie-breaking.
#pragma unroll
        for (int j = 0; j < Gg; ++j) {
            const float vv[4] = {a[j].x, a[j].y, a[j].z, a[j].w};
#pragma unroll
            for (int k = 0; k < 4; ++k) {
                const float val = vv[k];
                const bool gt1 = val > max1[j][k];
                const bool gt2 = val > max2[j][k];
                max2[j][k] = gt1 ? max1[j][k] : (gt2 ? val : max2[j][k]);
                idx2[j][k] = gt1 ? idx1[j][k] : (gt2 ? c   : idx2[j][k]);
                max1[j][k] = gt1 ? val        : max1[j][k];
                idx1[j][k] = gt1 ? c          : idx1[j][k];
            }
        }

        if (c + 1 < Cc) {
#pragma unroll
            for (int j = 0; j < Gg; ++j) a[j] = n[j];
        }
    }

    // ---- Gather the two selected disparity samples per pixel: issue all
    // before any use (data-dependent addresses; largely cache-absorbed
    // per FETCH_SIZE evidence). ----
    float d1[Gg][4], d2[Gg][4];
#pragma unroll
    for (int j = 0; j < Gg; ++j)
#pragma unroll
        for (int k = 0; k < 4; ++k) {
            d1[j][k] = db[j][(size_t)idx1[j][k] * HWp + k];
            d2[j][k] = db[j][(size_t)idx2[j][k] * HWp + k];
        }

#pragma unroll
    for (int j = 0; j < Gg; ++j) {
        float predo[4], p1o[4], p2o[4];
#pragma unroll
        for (int k = 0; k < 4; ++k) {
            // softmax over {max1, max2}: p1 = 1/(1+exp(m2-m1)), m2-m1 <= 0
            const float e  = __expf(max2[j][k] - max1[j][k]);
            const float p1 = 1.0f / (1.0f + e);
            const float p2 = 1.0f - p1;
            predo[k] = d1[j][k] * p1 + d2[j][k] * p2;
            p1o[k] = p1;
            p2o[k] = p2;
        }
        const int qj = qw + j * 256 + lane * 4;
        const int pj = b * HWp + qj;
        *(float4*)(pred + pj) = make_float4(predo[0], predo[1], predo[2], predo[3]);
        float* pb = prob + (size_t)b * 2 * HWp + qj;
        *(float4*)(pb)       = make_float4(p1o[0], p1o[1], p1o[2], p1o[3]);
        *(float4*)(pb + HWp) = make_float4(p2o[0], p2o[1], p2o[2], p2o[3]);
    }
}

extern "C" void kernel_launch(void* const* d_in, const int* in_sizes, int n_in,
                              void* d_out, int out_size, void* d_ws, size_t ws_size,
                              hipStream_t stream) {
    const float* cost = (const float*)d_in[0];
    const float* disp = (const float*)d_in[1];
    float* pred = (float*)d_out;          // first NPIX floats
    float* prob = (float*)d_out + NPIX;   // next 2*NPIX floats

    const int grid = NPIX / TILE;         // 800, exact
    sparse_regression_kernel<<<grid, BLK, 0, stream>>>(cost, disp, pred, prob);
}

// Round 5
// 322.370 us; speedup vs baseline: 1.2468x; 1.2468x over previous
//
#include <hip/hip_runtime.h>
#include <math.h>

// Problem constants (from reference setup_inputs)
#define Bb 8
#define Cc 24
#define Hh 320
#define Ww 640
#define HWp (Hh * Ww)        // 204800
#define NPIX (Bb * HWp)      // 1638400
#define PIX_PER_THREAD 4

// v6: eliminate the scattered disparity gather entirely.
// Evidence: v1-v4 (serial / reg-batch / fenced / guaranteed-async-MLP) all
// pin at 1.5-1.6 TB/s with both pipes idle; FETCH ~= cost only (disp gather
// L3-absorbed). The one structural feature all four share that a 6.3 TB/s
// copy doesn't: 3.3M scattered dword gathers, each occupying an L1 MSHR for
// a ~600cy L2/L3 round trip (~12.8K misses/CU / ~64 MSHRs -> ~50us of
// miss-queue serialization). Fix: indices are never an output, so carry the
// disparity VALUES through the top-2 scan instead. Per channel: two
// coalesced float4 loads (cost+disp); per-pixel state (m1,dv1,m2,dv2).
// Select booleans identical to v1 -> bit-identical results. Zero scatter.
// Traffic doubles to ~300MB but is 100% coalesced float4.
__global__ __launch_bounds__(256) void sparse_regression_kernel(
    const float* __restrict__ cost,
    const float* __restrict__ disp,
    float* __restrict__ pred,   // [B,H,W]   = NPIX floats
    float* __restrict__ prob)   // [B,2,H,W] = 2*NPIX floats
{
    const int t  = blockIdx.x * blockDim.x + threadIdx.x;
    const int p0 = t * PIX_PER_THREAD;
    if (p0 >= NPIX) return;

    const int b = p0 / HWp;          // 4-pixel groups never straddle b (HW%4==0)
    const int q = p0 - b * HWp;      // h*W + w

    const size_t base = (size_t)b * Cc * HWp + q;
    const float* cbase = cost + base;
    const float* dbase = disp + base;

    float m1[PIX_PER_THREAD], m2[PIX_PER_THREAD];
    float dv1[PIX_PER_THREAD], dv2[PIX_PER_THREAD];
#pragma unroll
    for (int j = 0; j < PIX_PER_THREAD; ++j) {
        m1[j] = -INFINITY; m2[j] = -INFINITY;
        dv1[j] = 0.0f;     dv2[j] = 0.0f;
    }

    // Streaming top-2 over channels, carrying the disparity values.
    // Strict '>' while scanning c ascending reproduces lax.top_k's
    // lower-index-wins tie-breaking (same booleans as the index version).
#pragma unroll
    for (int c = 0; c < Cc; ++c) {
        const float4 cv = *(const float4*)(cbase + (size_t)c * HWp);
        const float4 dv = *(const float4*)(dbase + (size_t)c * HWp);
        const float cc[4] = {cv.x, cv.y, cv.z, cv.w};
        const float dd[4] = {dv.x, dv.y, dv.z, dv.w};
#pragma unroll
        for (int j = 0; j < PIX_PER_THREAD; ++j) {
            const float val = cc[j];
            const float dvl = dd[j];
            const bool gt1 = val > m1[j];
            const bool gt2 = val > m2[j];
            m2[j]  = gt1 ? m1[j]  : (gt2 ? val : m2[j]);
            dv2[j] = gt1 ? dv1[j] : (gt2 ? dvl : dv2[j]);
            m1[j]  = gt1 ? val    : m1[j];
            dv1[j] = gt1 ? dvl    : dv1[j];
        }
    }

    float predo[PIX_PER_THREAD], p1o[PIX_PER_THREAD], p2o[PIX_PER_THREAD];
#pragma unroll
    for (int j = 0; j < PIX_PER_THREAD; ++j) {
        // softmax over {m1, m2}: p1 = 1/(1+exp(m2-m1)), m2-m1 <= 0
        const float e  = __expf(m2[j] - m1[j]);
        const float p1 = 1.0f / (1.0f + e);
        const float p2 = 1.0f - p1;
        predo[j] = dv1[j] * p1 + dv2[j] * p2;
        p1o[j] = p1;
        p2o[j] = p2;
    }

    // Coalesced float4 stores.
    *(float4*)(pred + p0) = make_float4(predo[0], predo[1], predo[2], predo[3]);
    float* pb = prob + (size_t)b * 2 * HWp + q;
    *(float4*)(pb)       = make_float4(p1o[0], p1o[1], p1o[2], p1o[3]);
    *(float4*)(pb + HWp) = make_float4(p2o[0], p2o[1], p2o[2], p2o[3]);
}

extern "C" void kernel_launch(void* const* d_in, const int* in_sizes, int n_in,
                              void* d_out, int out_size, void* d_ws, size_t ws_size,
                              hipStream_t stream) {
    const float* cost = (const float*)d_in[0];
    const float* disp = (const float*)d_in[1];
    float* pred = (float*)d_out;          // first NPIX floats
    float* prob = (float*)d_out + NPIX;   // next 2*NPIX floats

    const int threads = NPIX / PIX_PER_THREAD;   // 409600
    const int block = 256;
    const int grid = (threads + block - 1) / block;  // 1600
    sparse_regression_kernel<<<grid, block, 0, stream>>>(cost, disp, pred, prob);
}